// Round 1
// 1486.329 us; speedup vs baseline: 1.0621x; 1.0621x over previous
//
#include <hip/hip_runtime.h>
#include <hip/hip_bf16.h>

// Problem constants (fixed by the reference)
#define NN  131072      // nodes
#define GG  1024        // graphs
#define NPG 128         // nodes per graph
#define EE  4194304     // edges
#define DD  128         // input feature dim
#define CC  32          // per-layer conv width
#define NB  512         // CSR buckets (dst>>8), 256 nodes each
#define BTILE 4096      // edges per k_bin block
#define CAP 9600        // k_csr LDS staging capacity (mean 8192, sigma ~90)

typedef __hip_bfloat16 bf16;

// ---- dtype probe: classify x0's first 128 uint16s (bf16 vs f32 buffer) ----
__global__ void k_probe(const unsigned short* __restrict__ x, int* __restrict__ flag) {
    unsigned short u = x[threadIdx.x];
    int e = (u >> 7) & 0xFF;
    int q = (e >= 0x70 && e <= 0x85) ? 1 : 0;
    unsigned long long m = __ballot(q);
    __shared__ int cnt[2];
    if ((threadIdx.x & 63) == 0) cnt[threadIdx.x >> 6] = __popcll(m);
    __syncthreads();
    if (threadIdx.x == 0) flag[0] = (cnt[0] + cnt[1] >= 96) ? 1 : 0;  // 1 = bf16 mode
}

// ---- all weight tensors -> f32 scratch in one launch ----
struct PtrPack { const void* p[10]; };
__global__ void k_cvtall(PtrPack pk, float* __restrict__ wf, const int* __restrict__ flag) {
    int i = blockIdx.x * 256 + threadIdx.x;
    if (i >= 43490) return;
    const int off[11] = {0, 4096, 4128, 5152, 5184, 6208, 6240, 43104, 43232, 43488, 43490};
    int seg = 0;
    #pragma unroll
    for (int k = 1; k < 11; k++) if (i >= off[k]) seg = k;
    int local = i - off[seg];
    if (flag[0]) wf[i] = __bfloat162float(((const bf16*)pk.p[seg])[local]);
    else         wf[i] = ((const float*)pk.p[seg])[local];
}

// ================= bucket-sorted CSR build =================

// global bucket histogram of dst>>8 (LDS-staged)
__global__ void __launch_bounds__(256) k_hist(const int* __restrict__ ei, int* __restrict__ bhist) {
    __shared__ int h[NB];
    int tid = threadIdx.x;
    h[tid] = 0; h[tid + 256] = 0;
    __syncthreads();
    long t0 = (long)blockIdx.x * 8192;
    #pragma unroll 4
    for (int k = 0; k < 32; k++) {
        int e = t0 + k * 256 + tid;
        atomicAdd(&h[ei[EE + e] >> 8], 1);
    }
    __syncthreads();
    atomicAdd(&bhist[tid], h[tid]);
    atomicAdd(&bhist[tid + 256], h[tid + 256]);
}

// exclusive scan of bucket counts -> bbase[513], bcur copy
__global__ void __launch_bounds__(512) k_bscan(const int* __restrict__ bhist,
                                               int* __restrict__ bbase, int* __restrict__ bcur) {
    __shared__ int s[NB];
    int tid = threadIdx.x;
    int v = bhist[tid];
    s[tid] = v;
    __syncthreads();
    for (int o = 1; o < NB; o <<= 1) {
        int t = (tid >= o) ? s[tid - o] : 0;
        __syncthreads();
        s[tid] += t;
        __syncthreads();
    }
    bbase[tid] = s[tid] - v;
    bcur[tid] = s[tid] - v;
    if (tid == NB - 1) bbase[NB] = s[NB - 1];   // = EE
}

// bin edges into bucket-contiguous (dst,src) pair runs, LDS-staged for dense writes
__global__ void __launch_bounds__(512) k_bin(const int* __restrict__ ei,
                                             int* __restrict__ bcur, int2* __restrict__ ebuf) {
    __shared__ int hist[NB], loff[NB], gbase[NB], cur[NB];
    __shared__ int2 staged[BTILE];     // 32 KB
    int tid = threadIdx.x;
    long t0 = (long)blockIdx.x * BTILE;
    hist[tid] = 0;
    __syncthreads();
    int sreg[BTILE / 512], dreg[BTILE / 512];
    #pragma unroll
    for (int k = 0; k < BTILE / 512; k++) {
        int e = t0 + k * 512 + tid;
        sreg[k] = ei[e];
        dreg[k] = ei[EE + e];
        atomicAdd(&hist[dreg[k] >> 8], 1);
    }
    __syncthreads();
    int v = hist[tid];
    loff[tid] = v;
    __syncthreads();
    for (int o = 1; o < NB; o <<= 1) {
        int t = (tid >= o) ? loff[tid - o] : 0;
        __syncthreads();
        loff[tid] += t;
        __syncthreads();
    }
    gbase[tid] = atomicAdd(&bcur[tid], v);   // reserve global run for this block's bucket tid
    cur[tid] = 0;
    int excl = loff[tid] - v;
    __syncthreads();
    loff[tid] = excl;
    __syncthreads();
    #pragma unroll
    for (int k = 0; k < BTILE / 512; k++) {
        int b = dreg[k] >> 8;
        int r = atomicAdd(&cur[b], 1);
        staged[loff[b] + r] = make_int2(dreg[k], sreg[k]);
    }
    __syncthreads();
    #pragma unroll
    for (int k = 0; k < BTILE / 512; k++) {
        int t = k * 512 + tid;
        int2 p = staged[t];
        int b = p.x >> 8;
        ebuf[gbase[b] + (t - loff[b])] = p;   // contiguous runs per bucket
    }
}

// per-bucket counting sort -> col (coalesced), rowptr, dis, seed-neighbor marks
__global__ void __launch_bounds__(256) k_csr(const int* __restrict__ bbase,
                                             const int2* __restrict__ ebuf,
                                             int* __restrict__ rowptr, int* __restrict__ col,
                                             float* __restrict__ dis, int* __restrict__ mark) {
    __shared__ int hist[256], off[256], cur[256];
    __shared__ int lout[CAP];          // 38.4 KB
    int b = blockIdx.x, tid = threadIdx.x;
    int base = bbase[b];
    int n = bbase[b + 1] - base;
    hist[tid] = 0;
    __syncthreads();
    for (int t = tid; t < n; t += 256) {
        int2 p = ebuf[base + t];
        atomicAdd(&hist[p.x & 255], 1);
    }
    __syncthreads();
    int deg = hist[tid];
    off[tid] = deg;
    __syncthreads();
    for (int o = 1; o < 256; o <<= 1) {
        int t = (tid >= o) ? off[tid - o] : 0;
        __syncthreads();
        off[tid] += t;
        __syncthreads();
    }
    int excl = off[tid] - deg;
    int node = b * 256 + tid;
    rowptr[node] = base + excl;
    dis[node] = rsqrtf((float)deg + 1.0f);
    if (b == 0 && tid == 0) rowptr[NN] = EE;
    cur[tid] = 0;
    __syncthreads();
    off[tid] = excl;
    __syncthreads();
    bool fits = (n <= CAP);
    for (int t = tid; t < n; t += 256) {
        int2 p = ebuf[base + t];
        int d8 = p.x & 255;
        int r = off[d8] + atomicAdd(&cur[d8], 1);
        if (fits) lout[r] = p.y;
        else      col[base + r] = p.y;          // rare fallback
        if ((p.x & (NPG - 1)) == 0) mark[p.y] = 1;
    }
    __syncthreads();
    if (fits) for (int t = tid; t < n; t += 256) col[base + t] = lout[t];
}

// seeds + marked in-neighbors -> flist
__global__ void k_compact(const int* __restrict__ mark, int* __restrict__ flist,
                          int* __restrict__ fcnt) {
    int i = blockIdx.x * 256 + threadIdx.x;
    if (((i & (NPG - 1)) == 0) || mark[i]) flist[atomicAdd(fcnt, 1)] = i;
}

// ================= GEMMs (outputs pre-scaled by dis[row]) =================

__global__ void __launch_bounds__(256) k_gemm0(const void* __restrict__ x,
                                               const float* __restrict__ W,
                                               float* __restrict__ h,
                                               const float* __restrict__ dis,
                                               const int* __restrict__ flag) {
    __shared__ float Wl[DD * CC];
    __shared__ float xl[8 * DD];
    int tid = threadIdx.x;
    int bfm = flag[0];
    for (int t = tid; t < DD * CC; t += 256) Wl[t] = W[t];
    long rowbase = (long)blockIdx.x * 8;
    if (bfm) {
        const bf16* xp = (const bf16*)x;
        for (int t = tid; t < 8 * DD; t += 256) xl[t] = __bfloat162float(xp[rowbase * DD + t]);
    } else {
        const float* xp = (const float*)x;
        for (int t = tid; t < 8 * DD; t += 256) xl[t] = xp[rowbase * DD + t];
    }
    __syncthreads();
    int r = tid >> 5, c = tid & 31;
    float acc = 0.f;
    #pragma unroll 8
    for (int k = 0; k < DD; k++) acc += xl[r * DD + k] * Wl[k * CC + c];
    h[(rowbase + r) * CC + c] = acc * dis[rowbase + r];
}

__global__ void __launch_bounds__(256) k_gemm32(const float* __restrict__ hin,
                                                const float* __restrict__ W,
                                                float* __restrict__ hout,
                                                const float* __restrict__ dis) {
    __shared__ float Wl[CC * CC];
    __shared__ float xl[8 * CC];
    int tid = threadIdx.x;
    for (int t = tid; t < CC * CC; t += 256) Wl[t] = W[t];
    long rowbase = (long)blockIdx.x * 8;
    for (int t = tid; t < 8 * CC; t += 256) xl[t] = hin[rowbase * CC + t];
    __syncthreads();
    int r = tid >> 5, c = tid & 31;
    float acc = 0.f;
    #pragma unroll
    for (int k = 0; k < CC; k++) acc += xl[r * CC + k] * Wl[k * CC + c];
    hout[(rowbase + r) * CC + c] = acc * dis[rowbase + r];
}

__global__ void __launch_bounds__(256) k_gemm32l(const float* __restrict__ hin,
                                                 const float* __restrict__ W,
                                                 float* __restrict__ hout,
                                                 const float* __restrict__ dis,
                                                 const int* __restrict__ flist,
                                                 const int* __restrict__ fcnt) {
    int n = *fcnt;
    int base = blockIdx.x * 8;
    if (base >= n) return;
    __shared__ float Wl[CC * CC];
    __shared__ float xl[8 * CC];
    __shared__ int rows[8];
    int tid = threadIdx.x;
    for (int t = tid; t < CC * CC; t += 256) Wl[t] = W[t];
    if (tid < 8) rows[tid] = (base + tid < n) ? flist[base + tid] : flist[n - 1];
    __syncthreads();
    int r = tid >> 5, c = tid & 31;
    int row = rows[r];
    xl[tid] = hin[(long)row * CC + c];
    __syncthreads();
    float acc = 0.f;
    #pragma unroll
    for (int k = 0; k < CC; k++) acc += xl[r * CC + k] * Wl[k * CC + c];
    hout[(long)row * CC + c] = acc * dis[row];
}

// ================= CSR gather-aggregate: one WAVE per dst =================
// 64 lanes = 8 edge-slots x 8 feature-quads (float4). pbuf rows are pre-scaled
// by dis[src] in the GEMMs, so the gather is a pure float4 sum -> per edge just
// {col load (8-lane broadcast), one 128B row request}. 16 gathers in flight/wave.

__device__ __forceinline__ float4 gat_row4(const int* __restrict__ col,
                                           const float4* __restrict__ pb,
                                           int r0, int r1, int p, int q) {
    float ax = 0.f, ay = 0.f, az = 0.f, aw = 0.f;
    int e = r0 + p;
    for (; e + 8 < r1; e += 16) {
        int s0 = col[e], s1 = col[e + 8];
        float4 v0 = pb[(long)s0 * 8 + q];
        float4 v1 = pb[(long)s1 * 8 + q];
        ax += v0.x + v1.x; ay += v0.y + v1.y;
        az += v0.z + v1.z; aw += v0.w + v1.w;
    }
    if (e < r1) {
        float4 v = pb[(long)col[e] * 8 + q];
        ax += v.x; ay += v.y; az += v.z; aw += v.w;
    }
    #pragma unroll
    for (int m = 8; m < 64; m <<= 1) {   // combine the 8 edge-slots
        ax += __shfl_xor(ax, m);
        ay += __shfl_xor(ay, m);
        az += __shfl_xor(az, m);
        aw += __shfl_xor(aw, m);
    }
    return make_float4(ax, ay, az, aw);
}

__device__ __forceinline__ void gat_write(const float* __restrict__ dis,
                                          const float4* __restrict__ pb,
                                          const float* __restrict__ bias,
                                          float* __restrict__ hbuf,
                                          float* __restrict__ cat, int boff,
                                          int d, int q, float4 acc, bool wr_h) {
    float dd = dis[d];
    float4 ps = pb[(long)d * 8 + q];              // self term, pre-scaled = dis*h
    float4 bq = ((const float4*)bias)[q];
    float4 v;
    v.x = tanhf((acc.x + ps.x) * dd + bq.x);
    v.y = tanhf((acc.y + ps.y) * dd + bq.y);
    v.z = tanhf((acc.z + ps.z) * dd + bq.z);
    v.w = tanhf((acc.w + ps.w) * dd + bq.w);
    if (wr_h) ((float4*)hbuf)[(long)d * 8 + q] = v;
    if ((d & (NPG - 1)) == 0) ((float4*)(cat + (d >> 7) * 288 + boff))[q] = v;
}

__global__ void __launch_bounds__(256) k_gat_all(const int* __restrict__ rowptr,
                                                 const int* __restrict__ col,
                                                 const float* __restrict__ dis,
                                                 const float* __restrict__ pbuf,
                                                 const float* __restrict__ bias,
                                                 float* __restrict__ hbuf,
                                                 float* __restrict__ cat, int boff) {
    int tid = threadIdx.x;
    int d = blockIdx.x * 4 + (tid >> 6);
    int p = (tid >> 3) & 7, q = tid & 7;
    int r0 = rowptr[d], r1 = rowptr[d + 1];
    float4 acc = gat_row4(col, (const float4*)pbuf, r0, r1, p, q);
    if (p == 0) gat_write(dis, (const float4*)pbuf, bias, hbuf, cat, boff, d, q, acc, true);
}

__global__ void __launch_bounds__(256) k_gat_list(const int* __restrict__ rowptr,
                                                  const int* __restrict__ col,
                                                  const float* __restrict__ dis,
                                                  const float* __restrict__ pbuf,
                                                  const float* __restrict__ bias,
                                                  float* __restrict__ hbuf,
                                                  float* __restrict__ cat, int boff,
                                                  const int* __restrict__ flist,
                                                  const int* __restrict__ fcnt) {
    int tid = threadIdx.x;
    int idx = blockIdx.x * 4 + (tid >> 6);
    if (idx >= *fcnt) return;
    int d = flist[idx];
    int p = (tid >> 3) & 7, q = tid & 7;
    int r0 = rowptr[d], r1 = rowptr[d + 1];
    float4 acc = gat_row4(col, (const float4*)pbuf, r0, r1, p, q);
    if (p == 0) gat_write(dis, (const float4*)pbuf, bias, hbuf, cat, boff, d, q, acc, true);
}

__global__ void __launch_bounds__(256) k_gat_seed(const int* __restrict__ rowptr,
                                                  const int* __restrict__ col,
                                                  const float* __restrict__ dis,
                                                  const float* __restrict__ pbuf,
                                                  const float* __restrict__ bias,
                                                  float* __restrict__ cat, int boff) {
    int tid = threadIdx.x;
    int g = blockIdx.x * 4 + (tid >> 6);
    int d = g * NPG;
    int p = (tid >> 3) & 7, q = tid & 7;
    int r0 = rowptr[d], r1 = rowptr[d + 1];
    float4 acc = gat_row4(col, (const float4*)pbuf, r0, r1, p, q);
    if (p == 0) gat_write(dis, (const float4*)pbuf, bias, nullptr, cat, boff, d, q, acc, false);
}

// ================= head =================
__global__ void __launch_bounds__(128) k_head(const float* __restrict__ cat,
                                              const float* __restrict__ W1,
                                              const float* __restrict__ b1,
                                              const float* __restrict__ W2,
                                              const float* __restrict__ b2,
                                              const int* __restrict__ y,
                                              void* __restrict__ out,
                                              float* __restrict__ scal,
                                              const int* __restrict__ flag) {
    __shared__ float crow[288];
    __shared__ float red[4];
    int g = blockIdx.x, tid = threadIdx.x;
    int bfm = flag[0];
    for (int t = tid; t < 288; t += 128) crow[t] = cat[g * 288 + t];
    __syncthreads();
    float acc = 0.f;
    #pragma unroll 4
    for (int k = 0; k < 288; k++) acc += crow[k] * W1[k * 128 + tid];
    acc += b1[tid];
    if (bfm) ((bf16*)out)[2050 + g * 128 + tid] = __float2bfloat16(acc);
    else     ((float*)out)[2050 + g * 128 + tid] = acc;
    float r = fmaxf(acc, 0.f);
    float p0 = r * W2[tid * 2 + 0];
    float p1 = r * W2[tid * 2 + 1];
    for (int o = 32; o > 0; o >>= 1) {
        p0 += __shfl_down(p0, o);
        p1 += __shfl_down(p1, o);
    }
    if ((tid & 63) == 0) { red[(tid >> 6) * 2 + 0] = p0; red[(tid >> 6) * 2 + 1] = p1; }
    __syncthreads();
    if (tid == 0) {
        float l0 = red[0] + red[2] + b2[0];
        float l1 = red[1] + red[3] + b2[1];
        float m = fmaxf(l0, l1);
        float lse = m + logf(expf(l0 - m) + expf(l1 - m));
        float g0 = l0 - lse, g1 = l1 - lse;
        if (bfm) {
            ((bf16*)out)[g * 2 + 0] = __float2bfloat16(g0);
            ((bf16*)out)[g * 2 + 1] = __float2bfloat16(g1);
        } else {
            ((float*)out)[g * 2 + 0] = g0;
            ((float*)out)[g * 2 + 1] = g1;
        }
        int yy = y[g];
        atomicAdd(&scal[0], (yy == 0) ? -g0 : -g1);
        int pred = (l1 > l0) ? 1 : 0;
        if (pred == yy) atomicAdd(&scal[1], 1.0f);
    }
}

__global__ void k_fin(const float* __restrict__ scal, void* __restrict__ out,
                      const int* __restrict__ flag) {
    if (threadIdx.x == 0 && blockIdx.x == 0) {
        if (flag[0]) {
            ((bf16*)out)[2048] = __float2bfloat16(scal[0] / (float)GG);
            ((bf16*)out)[2049] = __float2bfloat16(scal[1] / (float)GG);
        } else {
            ((float*)out)[2048] = scal[0] / (float)GG;
            ((float*)out)[2049] = scal[1] / (float)GG;
        }
    }
}

extern "C" void kernel_launch(void* const* d_in, const int* in_sizes, int n_in,
                              void* d_out, int out_size, void* d_ws, size_t ws_size,
                              hipStream_t stream) {
    const void* x[3]  = {d_in[0], d_in[3], d_in[6]};
    const int*  ei[3] = {(const int*)d_in[1], (const int*)d_in[4], (const int*)d_in[7]};
    const int*  y     = (const int*)d_in[9];

    // ---- workspace carve-up ----
    int*   rowptr = (int*)d_ws;                // NN+2 (padded even)
    int*   col    = rowptr + NN + 2;           // EE
    int*   mark   = col + EE;                  // NN
    int*   flist  = mark + NN;                 // NN
    int*   fcnt   = flist + NN;                // 1
    int*   bhist  = fcnt + 1;                  // 512
    int*   bbase  = bhist + 512;               // 513
    int*   bcur   = bbase + 513;               // 512  (running total even)
    float* dis    = (float*)(bcur + 512);      // NN
    float* pbuf   = dis + NN;                  // NN*32   } ebuf (EE int2) overlays
    float* hbuf   = pbuf + (size_t)NN * CC;    // NN*32   } pbuf+hbuf exactly
    int2*  ebuf   = (int2*)pbuf;
    float* cat    = hbuf + (size_t)NN * CC;    // GG*288 (16B-aligned)
    float* scal   = cat + (size_t)GG * 288;    // 2
    int*   flag   = (int*)(scal + 2);          // 1 (+1 pad to keep wf 16B-aligned)
    float* wf     = (float*)(flag + 2);        // 43490
    float* fWc0 = wf;
    float* fbc0 = wf + 4096;
    float* fWc1 = wf + 4128;
    float* fbc1 = wf + 5152;
    float* fWc2 = wf + 5184;
    float* fbc2 = wf + 6208;
    float* fW1  = wf + 6240;
    float* fb1  = wf + 43104;
    float* fW2  = wf + 43232;
    float* fb2  = wf + 43488;
    size_t need = (size_t)((char*)(wf + 43490) - (char*)d_ws);
    if (ws_size < need) return;   // starved: leave out zero as a diagnostic

    k_probe<<<1, 128, 0, stream>>>((const unsigned short*)x[0], flag);
    PtrPack pk;
    for (int k = 0; k < 10; k++) pk.p[k] = d_in[10 + k];
    k_cvtall<<<170, 256, 0, stream>>>(pk, wf, flag);
    hipMemsetAsync(scal, 0, 2 * sizeof(float), stream);

    const float* fW[3] = {fWc0, fWc1, fWc2};
    const float* fb[3] = {fbc0, fbc1, fbc2};

    for (int b = 0; b < 3; b++) {
        // ---- bucket-sorted CSR build ----
        hipMemsetAsync(bhist, 0, NB * sizeof(int), stream);
        hipMemsetAsync(mark, 0, NN * sizeof(int), stream);
        hipMemsetAsync(fcnt, 0, sizeof(int), stream);
        k_hist<<<512, 256, 0, stream>>>(ei[b], bhist);
        k_bscan<<<1, 512, 0, stream>>>(bhist, bbase, bcur);
        k_bin<<<EE / BTILE, 512, 0, stream>>>(ei[b], bcur, ebuf);
        k_csr<<<NB, 256, 0, stream>>>(bbase, ebuf, rowptr, col, dis, mark);
        k_compact<<<NN / 256, 256, 0, stream>>>(mark, flist, fcnt);

        // ---- layer 1: full graph ----
        k_gemm0<<<NN / 8, 256, 0, stream>>>(x[b], fW[0], pbuf, dis, flag);
        k_gat_all<<<NN / 4, 256, 0, stream>>>(rowptr, col, dis, pbuf, fb[0], hbuf, cat, b * 96);
        // ---- layer 2: frontier only ----
        k_gemm32<<<NN / 8, 256, 0, stream>>>(hbuf, fW[1], pbuf, dis);
        k_gat_list<<<NN / 4, 256, 0, stream>>>(rowptr, col, dis, pbuf, fb[1], hbuf, cat,
                                               b * 96 + 32, flist, fcnt);
        // ---- layer 3: seeds only ----
        k_gemm32l<<<NN / 8, 256, 0, stream>>>(hbuf, fW[2], pbuf, dis, flist, fcnt);
        k_gat_seed<<<GG / 4, 256, 0, stream>>>(rowptr, col, dis, pbuf, fb[2], cat, b * 96 + 64);
    }

    k_head<<<GG, 128, 0, stream>>>(cat, fW1, fb1, fW2, fb2, y, d_out, scal, flag);
    k_fin<<<1, 64, 0, stream>>>(scal, d_out, flag);
}

// Round 2
// 1326.051 us; speedup vs baseline: 1.1905x; 1.1209x over previous
//
#include <hip/hip_runtime.h>
#include <hip/hip_bf16.h>
#include <hip/hip_fp16.h>

// Problem constants (fixed by the reference)
#define NN  131072      // nodes
#define GG  1024        // graphs
#define NPG 128         // nodes per graph
#define EE  4194304     // edges
#define DD  128         // input feature dim
#define CC  32          // per-layer conv width
#define NB  512         // CSR buckets (dst>>8), 256 nodes each
#define BTILE 4096      // edges per k_bin block
#define CAP 9600        // k_csr LDS staging capacity (mean 8192, sigma ~90)

typedef __hip_bfloat16 bf16;

// ---- dtype probe: classify x0's first 128 uint16s (bf16 vs f32 buffer) ----
__global__ void k_probe(const unsigned short* __restrict__ x, int* __restrict__ flag) {
    unsigned short u = x[threadIdx.x];
    int e = (u >> 7) & 0xFF;
    int q = (e >= 0x70 && e <= 0x85) ? 1 : 0;
    unsigned long long m = __ballot(q);
    __shared__ int cnt[2];
    if ((threadIdx.x & 63) == 0) cnt[threadIdx.x >> 6] = __popcll(m);
    __syncthreads();
    if (threadIdx.x == 0) flag[0] = (cnt[0] + cnt[1] >= 96) ? 1 : 0;  // 1 = bf16 mode
}

// ---- all weight tensors -> f32 scratch in one launch ----
struct PtrPack { const void* p[10]; };
__global__ void k_cvtall(PtrPack pk, float* __restrict__ wf, const int* __restrict__ flag) {
    int i = blockIdx.x * 256 + threadIdx.x;
    if (i >= 43490) return;
    const int off[11] = {0, 4096, 4128, 5152, 5184, 6208, 6240, 43104, 43232, 43488, 43490};
    int seg = 0;
    #pragma unroll
    for (int k = 1; k < 11; k++) if (i >= off[k]) seg = k;
    int local = i - off[seg];
    if (flag[0]) wf[i] = __bfloat162float(((const bf16*)pk.p[seg])[local]);
    else         wf[i] = ((const float*)pk.p[seg])[local];
}

// ================= bucket-sorted CSR build =================

// global bucket histogram of dst>>8 (LDS-staged)
__global__ void __launch_bounds__(256) k_hist(const int* __restrict__ ei, int* __restrict__ bhist) {
    __shared__ int h[NB];
    int tid = threadIdx.x;
    h[tid] = 0; h[tid + 256] = 0;
    __syncthreads();
    long t0 = (long)blockIdx.x * 8192;
    #pragma unroll 4
    for (int k = 0; k < 32; k++) {
        int e = t0 + k * 256 + tid;
        atomicAdd(&h[ei[EE + e] >> 8], 1);
    }
    __syncthreads();
    atomicAdd(&bhist[tid], h[tid]);
    atomicAdd(&bhist[tid + 256], h[tid + 256]);
}

// exclusive scan of bucket counts -> bbase[513], bcur copy
__global__ void __launch_bounds__(512) k_bscan(const int* __restrict__ bhist,
                                               int* __restrict__ bbase, int* __restrict__ bcur) {
    __shared__ int s[NB];
    int tid = threadIdx.x;
    int v = bhist[tid];
    s[tid] = v;
    __syncthreads();
    for (int o = 1; o < NB; o <<= 1) {
        int t = (tid >= o) ? s[tid - o] : 0;
        __syncthreads();
        s[tid] += t;
        __syncthreads();
    }
    bbase[tid] = s[tid] - v;
    bcur[tid] = s[tid] - v;
    if (tid == NB - 1) bbase[NB] = s[NB - 1];   // = EE
}

// bin edges into bucket-contiguous (dst,src) pair runs, LDS-staged for dense writes
__global__ void __launch_bounds__(512) k_bin(const int* __restrict__ ei,
                                             int* __restrict__ bcur, int2* __restrict__ ebuf) {
    __shared__ int hist[NB], loff[NB], gbase[NB], cur[NB];
    __shared__ int2 staged[BTILE];     // 32 KB
    int tid = threadIdx.x;
    long t0 = (long)blockIdx.x * BTILE;
    hist[tid] = 0;
    __syncthreads();
    int sreg[BTILE / 512], dreg[BTILE / 512];
    #pragma unroll
    for (int k = 0; k < BTILE / 512; k++) {
        int e = t0 + k * 512 + tid;
        sreg[k] = ei[e];
        dreg[k] = ei[EE + e];
        atomicAdd(&hist[dreg[k] >> 8], 1);
    }
    __syncthreads();
    int v = hist[tid];
    loff[tid] = v;
    __syncthreads();
    for (int o = 1; o < NB; o <<= 1) {
        int t = (tid >= o) ? loff[tid - o] : 0;
        __syncthreads();
        loff[tid] += t;
        __syncthreads();
    }
    gbase[tid] = atomicAdd(&bcur[tid], v);   // reserve global run for this block's bucket tid
    cur[tid] = 0;
    int excl = loff[tid] - v;
    __syncthreads();
    loff[tid] = excl;
    __syncthreads();
    #pragma unroll
    for (int k = 0; k < BTILE / 512; k++) {
        int b = dreg[k] >> 8;
        int r = atomicAdd(&cur[b], 1);
        staged[loff[b] + r] = make_int2(dreg[k], sreg[k]);
    }
    __syncthreads();
    #pragma unroll
    for (int k = 0; k < BTILE / 512; k++) {
        int t = k * 512 + tid;
        int2 p = staged[t];
        int b = p.x >> 8;
        ebuf[gbase[b] + (t - loff[b])] = p;   // contiguous runs per bucket
    }
}

// per-bucket counting sort -> col (coalesced), rowptr, dis, seed-neighbor marks
__global__ void __launch_bounds__(256) k_csr(const int* __restrict__ bbase,
                                             const int2* __restrict__ ebuf,
                                             int* __restrict__ rowptr, int* __restrict__ col,
                                             float* __restrict__ dis, int* __restrict__ mark) {
    __shared__ int hist[256], off[256], cur[256];
    __shared__ int lout[CAP];          // 38.4 KB
    int b = blockIdx.x, tid = threadIdx.x;
    int base = bbase[b];
    int n = bbase[b + 1] - base;
    hist[tid] = 0;
    __syncthreads();
    for (int t = tid; t < n; t += 256) {
        int2 p = ebuf[base + t];
        atomicAdd(&hist[p.x & 255], 1);
    }
    __syncthreads();
    int deg = hist[tid];
    off[tid] = deg;
    __syncthreads();
    for (int o = 1; o < 256; o <<= 1) {
        int t = (tid >= o) ? off[tid - o] : 0;
        __syncthreads();
        off[tid] += t;
        __syncthreads();
    }
    int excl = off[tid] - deg;
    int node = b * 256 + tid;
    rowptr[node] = base + excl;
    dis[node] = rsqrtf((float)deg + 1.0f);
    if (b == 0 && tid == 0) rowptr[NN] = EE;
    cur[tid] = 0;
    __syncthreads();
    off[tid] = excl;
    __syncthreads();
    bool fits = (n <= CAP);
    for (int t = tid; t < n; t += 256) {
        int2 p = ebuf[base + t];
        int d8 = p.x & 255;
        int r = off[d8] + atomicAdd(&cur[d8], 1);
        if (fits) lout[r] = p.y;
        else      col[base + r] = p.y;          // rare fallback
        if ((p.x & (NPG - 1)) == 0) mark[p.y] = 1;
    }
    __syncthreads();
    if (fits) for (int t = tid; t < n; t += 256) col[base + t] = lout[t];
}

// seeds + marked in-neighbors -> flist
__global__ void k_compact(const int* __restrict__ mark, int* __restrict__ flist,
                          int* __restrict__ fcnt) {
    int i = blockIdx.x * 256 + threadIdx.x;
    if (((i & (NPG - 1)) == 0) || mark[i]) flist[atomicAdd(fcnt, 1)] = i;
}

// ================= GEMMs (outputs pre-scaled by dis[row], stored fp16) =================
// fp16 payload: values are dis*(h@W), |v| < ~8 -> comfortably in fp16 range.
// fp16 mantissa (2^-11) keeps added absmax ~2e-4 (bf16's 2^-9 would risk threshold).

__global__ void __launch_bounds__(256) k_gemm0(const void* __restrict__ x,
                                               const float* __restrict__ W,
                                               __half* __restrict__ h,
                                               const float* __restrict__ dis,
                                               const int* __restrict__ flag) {
    __shared__ float Wl[DD * CC];
    __shared__ float xl[8 * DD];
    int tid = threadIdx.x;
    int bfm = flag[0];
    for (int t = tid; t < DD * CC; t += 256) Wl[t] = W[t];
    long rowbase = (long)blockIdx.x * 8;
    if (bfm) {
        const bf16* xp = (const bf16*)x;
        for (int t = tid; t < 8 * DD; t += 256) xl[t] = __bfloat162float(xp[rowbase * DD + t]);
    } else {
        const float* xp = (const float*)x;
        for (int t = tid; t < 8 * DD; t += 256) xl[t] = xp[rowbase * DD + t];
    }
    __syncthreads();
    int r = tid >> 5, c = tid & 31;
    float acc = 0.f;
    #pragma unroll 8
    for (int k = 0; k < DD; k++) acc += xl[r * DD + k] * Wl[k * CC + c];
    h[(rowbase + r) * CC + c] = __float2half(acc * dis[rowbase + r]);
}

__global__ void __launch_bounds__(256) k_gemm32(const float* __restrict__ hin,
                                                const float* __restrict__ W,
                                                __half* __restrict__ hout,
                                                const float* __restrict__ dis) {
    __shared__ float Wl[CC * CC];
    __shared__ float xl[8 * CC];
    int tid = threadIdx.x;
    for (int t = tid; t < CC * CC; t += 256) Wl[t] = W[t];
    long rowbase = (long)blockIdx.x * 8;
    for (int t = tid; t < 8 * CC; t += 256) xl[t] = hin[rowbase * CC + t];
    __syncthreads();
    int r = tid >> 5, c = tid & 31;
    float acc = 0.f;
    #pragma unroll
    for (int k = 0; k < CC; k++) acc += xl[r * CC + k] * Wl[k * CC + c];
    hout[(rowbase + r) * CC + c] = __float2half(acc * dis[rowbase + r]);
}

__global__ void __launch_bounds__(256) k_gemm32l(const float* __restrict__ hin,
                                                 const float* __restrict__ W,
                                                 __half* __restrict__ hout,
                                                 const float* __restrict__ dis,
                                                 const int* __restrict__ flist,
                                                 const int* __restrict__ fcnt) {
    int n = *fcnt;
    int base = blockIdx.x * 8;
    if (base >= n) return;
    __shared__ float Wl[CC * CC];
    __shared__ float xl[8 * CC];
    __shared__ int rows[8];
    int tid = threadIdx.x;
    for (int t = tid; t < CC * CC; t += 256) Wl[t] = W[t];
    if (tid < 8) rows[tid] = (base + tid < n) ? flist[base + tid] : flist[n - 1];
    __syncthreads();
    int r = tid >> 5, c = tid & 31;
    int row = rows[r];
    xl[tid] = hin[(long)row * CC + c];
    __syncthreads();
    float acc = 0.f;
    #pragma unroll
    for (int k = 0; k < CC; k++) acc += xl[r * CC + k] * Wl[k * CC + c];
    hout[(long)row * CC + c] = __float2half(acc * dis[row]);
}

// ================= CSR gather-aggregate: one WAVE per dst =================
// 64 lanes = 8 edge-slots x 8 feature-quads. pbuf rows are fp16, pre-scaled by
// dis[src] -> per edge: {col load, one coalesced 64B row request}. fp32 accum.

__device__ __forceinline__ void acc_h4(float2 raw, float& ax, float& ay,
                                       float& az, float& aw) {
    __half2* h = reinterpret_cast<__half2*>(&raw);
    float2 a = __half22float2(h[0]);
    float2 b = __half22float2(h[1]);
    ax += a.x; ay += a.y; az += b.x; aw += b.y;
}

__device__ __forceinline__ float4 gat_row4(const int* __restrict__ col,
                                           const float2* __restrict__ pb,
                                           int r0, int r1, int p, int q) {
    float ax = 0.f, ay = 0.f, az = 0.f, aw = 0.f;
    int e = r0 + p;
    for (; e + 8 < r1; e += 16) {
        int s0 = col[e], s1 = col[e + 8];
        float2 v0 = pb[(long)s0 * 8 + q];
        float2 v1 = pb[(long)s1 * 8 + q];
        acc_h4(v0, ax, ay, az, aw);
        acc_h4(v1, ax, ay, az, aw);
    }
    if (e < r1) {
        float2 v = pb[(long)col[e] * 8 + q];
        acc_h4(v, ax, ay, az, aw);
    }
    #pragma unroll
    for (int m = 8; m < 64; m <<= 1) {   // combine the 8 edge-slots
        ax += __shfl_xor(ax, m);
        ay += __shfl_xor(ay, m);
        az += __shfl_xor(az, m);
        aw += __shfl_xor(aw, m);
    }
    return make_float4(ax, ay, az, aw);
}

__device__ __forceinline__ void gat_write(const float* __restrict__ dis,
                                          const float2* __restrict__ pb,
                                          const float* __restrict__ bias,
                                          float* __restrict__ hbuf,
                                          float* __restrict__ cat, int boff,
                                          int d, int q, float4 acc, bool wr_h) {
    float dd = dis[d];
    float sx = 0.f, sy = 0.f, sz = 0.f, sw = 0.f;
    acc_h4(pb[(long)d * 8 + q], sx, sy, sz, sw);   // self term, pre-scaled = dis*h
    float4 bq = ((const float4*)bias)[q];
    float4 v;
    v.x = tanhf((acc.x + sx) * dd + bq.x);
    v.y = tanhf((acc.y + sy) * dd + bq.y);
    v.z = tanhf((acc.z + sz) * dd + bq.z);
    v.w = tanhf((acc.w + sw) * dd + bq.w);
    if (wr_h) ((float4*)hbuf)[(long)d * 8 + q] = v;
    if ((d & (NPG - 1)) == 0) ((float4*)(cat + (d >> 7) * 288 + boff))[q] = v;
}

__global__ void __launch_bounds__(256) k_gat_all(const int* __restrict__ rowptr,
                                                 const int* __restrict__ col,
                                                 const float* __restrict__ dis,
                                                 const __half* __restrict__ pbuf,
                                                 const float* __restrict__ bias,
                                                 float* __restrict__ hbuf,
                                                 float* __restrict__ cat, int boff) {
    int tid = threadIdx.x;
    int d = blockIdx.x * 4 + (tid >> 6);
    int p = (tid >> 3) & 7, q = tid & 7;
    int r0 = rowptr[d], r1 = rowptr[d + 1];
    const float2* pb = (const float2*)pbuf;
    float4 acc = gat_row4(col, pb, r0, r1, p, q);
    if (p == 0) gat_write(dis, pb, bias, hbuf, cat, boff, d, q, acc, true);
}

__global__ void __launch_bounds__(256) k_gat_list(const int* __restrict__ rowptr,
                                                  const int* __restrict__ col,
                                                  const float* __restrict__ dis,
                                                  const __half* __restrict__ pbuf,
                                                  const float* __restrict__ bias,
                                                  float* __restrict__ hbuf,
                                                  float* __restrict__ cat, int boff,
                                                  const int* __restrict__ flist,
                                                  const int* __restrict__ fcnt) {
    int tid = threadIdx.x;
    int idx = blockIdx.x * 4 + (tid >> 6);
    if (idx >= *fcnt) return;
    int d = flist[idx];
    int p = (tid >> 3) & 7, q = tid & 7;
    int r0 = rowptr[d], r1 = rowptr[d + 1];
    const float2* pb = (const float2*)pbuf;
    float4 acc = gat_row4(col, pb, r0, r1, p, q);
    if (p == 0) gat_write(dis, pb, bias, hbuf, cat, boff, d, q, acc, true);
}

__global__ void __launch_bounds__(256) k_gat_seed(const int* __restrict__ rowptr,
                                                  const int* __restrict__ col,
                                                  const float* __restrict__ dis,
                                                  const __half* __restrict__ pbuf,
                                                  const float* __restrict__ bias,
                                                  float* __restrict__ cat, int boff) {
    int tid = threadIdx.x;
    int g = blockIdx.x * 4 + (tid >> 6);
    int d = g * NPG;
    int p = (tid >> 3) & 7, q = tid & 7;
    int r0 = rowptr[d], r1 = rowptr[d + 1];
    const float2* pb = (const float2*)pbuf;
    float4 acc = gat_row4(col, pb, r0, r1, p, q);
    if (p == 0) gat_write(dis, pb, bias, nullptr, cat, boff, d, q, acc, false);
}

// ================= head =================
__global__ void __launch_bounds__(128) k_head(const float* __restrict__ cat,
                                              const float* __restrict__ W1,
                                              const float* __restrict__ b1,
                                              const float* __restrict__ W2,
                                              const float* __restrict__ b2,
                                              const int* __restrict__ y,
                                              void* __restrict__ out,
                                              float* __restrict__ scal,
                                              const int* __restrict__ flag) {
    __shared__ float crow[288];
    __shared__ float red[4];
    int g = blockIdx.x, tid = threadIdx.x;
    int bfm = flag[0];
    for (int t = tid; t < 288; t += 128) crow[t] = cat[g * 288 + t];
    __syncthreads();
    float acc = 0.f;
    #pragma unroll 4
    for (int k = 0; k < 288; k++) acc += crow[k] * W1[k * 128 + tid];
    acc += b1[tid];
    if (bfm) ((bf16*)out)[2050 + g * 128 + tid] = __float2bfloat16(acc);
    else     ((float*)out)[2050 + g * 128 + tid] = acc;
    float r = fmaxf(acc, 0.f);
    float p0 = r * W2[tid * 2 + 0];
    float p1 = r * W2[tid * 2 + 1];
    for (int o = 32; o > 0; o >>= 1) {
        p0 += __shfl_down(p0, o);
        p1 += __shfl_down(p1, o);
    }
    if ((tid & 63) == 0) { red[(tid >> 6) * 2 + 0] = p0; red[(tid >> 6) * 2 + 1] = p1; }
    __syncthreads();
    if (tid == 0) {
        float l0 = red[0] + red[2] + b2[0];
        float l1 = red[1] + red[3] + b2[1];
        float m = fmaxf(l0, l1);
        float lse = m + logf(expf(l0 - m) + expf(l1 - m));
        float g0 = l0 - lse, g1 = l1 - lse;
        if (bfm) {
            ((bf16*)out)[g * 2 + 0] = __float2bfloat16(g0);
            ((bf16*)out)[g * 2 + 1] = __float2bfloat16(g1);
        } else {
            ((float*)out)[g * 2 + 0] = g0;
            ((float*)out)[g * 2 + 1] = g1;
        }
        int yy = y[g];
        atomicAdd(&scal[0], (yy == 0) ? -g0 : -g1);
        int pred = (l1 > l0) ? 1 : 0;
        if (pred == yy) atomicAdd(&scal[1], 1.0f);
    }
}

__global__ void k_fin(const float* __restrict__ scal, void* __restrict__ out,
                      const int* __restrict__ flag) {
    if (threadIdx.x == 0 && blockIdx.x == 0) {
        if (flag[0]) {
            ((bf16*)out)[2048] = __float2bfloat16(scal[0] / (float)GG);
            ((bf16*)out)[2049] = __float2bfloat16(scal[1] / (float)GG);
        } else {
            ((float*)out)[2048] = scal[0] / (float)GG;
            ((float*)out)[2049] = scal[1] / (float)GG;
        }
    }
}

extern "C" void kernel_launch(void* const* d_in, const int* in_sizes, int n_in,
                              void* d_out, int out_size, void* d_ws, size_t ws_size,
                              hipStream_t stream) {
    const void* x[3]  = {d_in[0], d_in[3], d_in[6]};
    const int*  ei[3] = {(const int*)d_in[1], (const int*)d_in[4], (const int*)d_in[7]};
    const int*  y     = (const int*)d_in[9];

    // ---- workspace carve-up ----
    int*   rowptr = (int*)d_ws;                // NN+2 (padded even)
    int*   col    = rowptr + NN + 2;           // EE
    int*   mark   = col + EE;                  // NN
    int*   flist  = mark + NN;                 // NN
    int*   fcnt   = flist + NN;                // 1
    int*   bhist  = fcnt + 1;                  // 512
    int*   bbase  = bhist + 512;               // 513
    int*   bcur   = bbase + 513;               // 512  (running total even)
    float* dis    = (float*)(bcur + 512);      // NN
    float* pbuf   = dis + NN;                  // NN*32 floats reserved; fp16 uses half } ebuf overlays
    float* hbuf   = pbuf + (size_t)NN * CC;    // NN*32 fp32                            } pbuf+hbuf
    int2*  ebuf   = (int2*)pbuf;               // EE int2 = exactly pbuf+hbuf region
    __half* pbufh = (__half*)pbuf;             // fp16 gather payload (first 8MB of pbuf region)
    float* cat    = hbuf + (size_t)NN * CC;    // GG*288 (16B-aligned)
    float* scal   = cat + (size_t)GG * 288;    // 2
    int*   flag   = (int*)(scal + 2);          // 1 (+1 pad to keep wf 16B-aligned)
    float* wf     = (float*)(flag + 2);        // 43490
    float* fWc0 = wf;
    float* fbc0 = wf + 4096;
    float* fWc1 = wf + 4128;
    float* fbc1 = wf + 5152;
    float* fWc2 = wf + 5184;
    float* fbc2 = wf + 6208;
    float* fW1  = wf + 6240;
    float* fb1  = wf + 43104;
    float* fW2  = wf + 43232;
    float* fb2  = wf + 43488;
    size_t need = (size_t)((char*)(wf + 43490) - (char*)d_ws);
    if (ws_size < need) return;   // starved: leave out zero as a diagnostic

    k_probe<<<1, 128, 0, stream>>>((const unsigned short*)x[0], flag);
    PtrPack pk;
    for (int k = 0; k < 10; k++) pk.p[k] = d_in[10 + k];
    k_cvtall<<<170, 256, 0, stream>>>(pk, wf, flag);
    hipMemsetAsync(scal, 0, 2 * sizeof(float), stream);

    const float* fW[3] = {fWc0, fWc1, fWc2};
    const float* fb[3] = {fbc0, fbc1, fbc2};

    for (int b = 0; b < 3; b++) {
        // ---- bucket-sorted CSR build ----
        hipMemsetAsync(bhist, 0, NB * sizeof(int), stream);
        hipMemsetAsync(mark, 0, NN * sizeof(int), stream);
        hipMemsetAsync(fcnt, 0, sizeof(int), stream);
        k_hist<<<512, 256, 0, stream>>>(ei[b], bhist);
        k_bscan<<<1, 512, 0, stream>>>(bhist, bbase, bcur);
        k_bin<<<EE / BTILE, 512, 0, stream>>>(ei[b], bcur, ebuf);
        k_csr<<<NB, 256, 0, stream>>>(bbase, ebuf, rowptr, col, dis, mark);
        k_compact<<<NN / 256, 256, 0, stream>>>(mark, flist, fcnt);

        // ---- layer 1: full graph ----
        k_gemm0<<<NN / 8, 256, 0, stream>>>(x[b], fW[0], pbufh, dis, flag);
        k_gat_all<<<NN / 4, 256, 0, stream>>>(rowptr, col, dis, pbufh, fb[0], hbuf, cat, b * 96);
        // ---- layer 2: frontier only ----
        k_gemm32<<<NN / 8, 256, 0, stream>>>(hbuf, fW[1], pbufh, dis);
        k_gat_list<<<NN / 4, 256, 0, stream>>>(rowptr, col, dis, pbufh, fb[1], hbuf, cat,
                                               b * 96 + 32, flist, fcnt);
        // ---- layer 3: seeds only ----
        k_gemm32l<<<NN / 8, 256, 0, stream>>>(hbuf, fW[2], pbufh, dis, flist, fcnt);
        k_gat_seed<<<GG / 4, 256, 0, stream>>>(rowptr, col, dis, pbufh, fb[2], cat, b * 96 + 64);
    }

    k_head<<<GG, 128, 0, stream>>>(cat, fW1, fb1, fW2, fb2, y, d_out, scal, flag);
    k_fin<<<1, 64, 0, stream>>>(scal, d_out, flag);
}

// Round 3
// 1182.416 us; speedup vs baseline: 1.3352x; 1.1215x over previous
//
#include <hip/hip_runtime.h>
#include <hip/hip_bf16.h>
#include <hip/hip_fp16.h>

// Problem constants (fixed by the reference)
#define NN  131072      // nodes
#define GG  1024        // graphs
#define NPG 128         // nodes per graph
#define EE  4194304     // edges
#define DD  128         // input feature dim
#define CC  32          // per-layer conv width
#define NB  512         // CSR buckets (dst>>8), 256 nodes each
#define BTILE 4096      // edges per k_bin block
#define CAP 9600        // k_csr LDS staging capacity (mean 8192, sigma ~90)

typedef __hip_bfloat16 bf16;

// ---- dtype probe: classify x0's first 128 uint16s (bf16 vs f32 buffer) ----
__global__ void k_probe(const unsigned short* __restrict__ x, int* __restrict__ flag) {
    unsigned short u = x[threadIdx.x];
    int e = (u >> 7) & 0xFF;
    int q = (e >= 0x70 && e <= 0x85) ? 1 : 0;
    unsigned long long m = __ballot(q);
    __shared__ int cnt[2];
    if ((threadIdx.x & 63) == 0) cnt[threadIdx.x >> 6] = __popcll(m);
    __syncthreads();
    if (threadIdx.x == 0) flag[0] = (cnt[0] + cnt[1] >= 96) ? 1 : 0;  // 1 = bf16 mode
}

// ---- all weight tensors -> f32 scratch in one launch ----
struct PtrPack { const void* p[10]; };
__global__ void k_cvtall(PtrPack pk, float* __restrict__ wf, const int* __restrict__ flag) {
    int i = blockIdx.x * 256 + threadIdx.x;
    if (i >= 43490) return;
    const int off[11] = {0, 4096, 4128, 5152, 5184, 6208, 6240, 43104, 43232, 43488, 43490};
    int seg = 0;
    #pragma unroll
    for (int k = 1; k < 11; k++) if (i >= off[k]) seg = k;
    int local = i - off[seg];
    if (flag[0]) wf[i] = __bfloat162float(((const bf16*)pk.p[seg])[local]);
    else         wf[i] = ((const float*)pk.p[seg])[local];
}

// ================= bucket-sorted CSR build =================

// global bucket histogram of dst>>8 (LDS-staged)
__global__ void __launch_bounds__(256) k_hist(const int* __restrict__ ei, int* __restrict__ bhist) {
    __shared__ int h[NB];
    int tid = threadIdx.x;
    h[tid] = 0; h[tid + 256] = 0;
    __syncthreads();
    long t0 = (long)blockIdx.x * 8192;
    #pragma unroll 4
    for (int k = 0; k < 32; k++) {
        int e = t0 + k * 256 + tid;
        atomicAdd(&h[ei[EE + e] >> 8], 1);
    }
    __syncthreads();
    atomicAdd(&bhist[tid], h[tid]);
    atomicAdd(&bhist[tid + 256], h[tid + 256]);
}

// exclusive scan of bucket counts -> bbase[513], bcur copy
__global__ void __launch_bounds__(512) k_bscan(const int* __restrict__ bhist,
                                               int* __restrict__ bbase, int* __restrict__ bcur) {
    __shared__ int s[NB];
    int tid = threadIdx.x;
    int v = bhist[tid];
    s[tid] = v;
    __syncthreads();
    for (int o = 1; o < NB; o <<= 1) {
        int t = (tid >= o) ? s[tid - o] : 0;
        __syncthreads();
        s[tid] += t;
        __syncthreads();
    }
    bbase[tid] = s[tid] - v;
    bcur[tid] = s[tid] - v;
    if (tid == NB - 1) bbase[NB] = s[NB - 1];   // = EE
}

// bin edges into bucket-contiguous (dst,src) pair runs, LDS-staged for dense writes
__global__ void __launch_bounds__(512) k_bin(const int* __restrict__ ei,
                                             int* __restrict__ bcur, int2* __restrict__ ebuf) {
    __shared__ int hist[NB], loff[NB], gbase[NB], cur[NB];
    __shared__ int2 staged[BTILE];     // 32 KB
    int tid = threadIdx.x;
    long t0 = (long)blockIdx.x * BTILE;
    hist[tid] = 0;
    __syncthreads();
    int sreg[BTILE / 512], dreg[BTILE / 512];
    #pragma unroll
    for (int k = 0; k < BTILE / 512; k++) {
        int e = t0 + k * 512 + tid;
        sreg[k] = ei[e];
        dreg[k] = ei[EE + e];
        atomicAdd(&hist[dreg[k] >> 8], 1);
    }
    __syncthreads();
    int v = hist[tid];
    loff[tid] = v;
    __syncthreads();
    for (int o = 1; o < NB; o <<= 1) {
        int t = (tid >= o) ? loff[tid - o] : 0;
        __syncthreads();
        loff[tid] += t;
        __syncthreads();
    }
    gbase[tid] = atomicAdd(&bcur[tid], v);   // reserve global run for this block's bucket tid
    cur[tid] = 0;
    int excl = loff[tid] - v;
    __syncthreads();
    loff[tid] = excl;
    __syncthreads();
    #pragma unroll
    for (int k = 0; k < BTILE / 512; k++) {
        int b = dreg[k] >> 8;
        int r = atomicAdd(&cur[b], 1);
        staged[loff[b] + r] = make_int2(dreg[k], sreg[k]);
    }
    __syncthreads();
    #pragma unroll
    for (int k = 0; k < BTILE / 512; k++) {
        int t = k * 512 + tid;
        int2 p = staged[t];
        int b = p.x >> 8;
        ebuf[gbase[b] + (t - loff[b])] = p;   // contiguous runs per bucket
    }
}

// per-bucket counting sort -> col (coalesced), rowptr, dis, seed-neighbor marks
__global__ void __launch_bounds__(256) k_csr(const int* __restrict__ bbase,
                                             const int2* __restrict__ ebuf,
                                             int* __restrict__ rowptr, int* __restrict__ col,
                                             float* __restrict__ dis, int* __restrict__ mark) {
    __shared__ int hist[256], off[256], cur[256];
    __shared__ int lout[CAP];          // 38.4 KB
    int b = blockIdx.x, tid = threadIdx.x;
    int base = bbase[b];
    int n = bbase[b + 1] - base;
    hist[tid] = 0;
    __syncthreads();
    for (int t = tid; t < n; t += 256) {
        int2 p = ebuf[base + t];
        atomicAdd(&hist[p.x & 255], 1);
    }
    __syncthreads();
    int deg = hist[tid];
    off[tid] = deg;
    __syncthreads();
    for (int o = 1; o < 256; o <<= 1) {
        int t = (tid >= o) ? off[tid - o] : 0;
        __syncthreads();
        off[tid] += t;
        __syncthreads();
    }
    int excl = off[tid] - deg;
    int node = b * 256 + tid;
    rowptr[node] = base + excl;
    dis[node] = rsqrtf((float)deg + 1.0f);
    if (b == 0 && tid == 0) rowptr[NN] = EE;
    cur[tid] = 0;
    __syncthreads();
    off[tid] = excl;
    __syncthreads();
    bool fits = (n <= CAP);
    for (int t = tid; t < n; t += 256) {
        int2 p = ebuf[base + t];
        int d8 = p.x & 255;
        int r = off[d8] + atomicAdd(&cur[d8], 1);
        if (fits) lout[r] = p.y;
        else      col[base + r] = p.y;          // rare fallback
        if ((p.x & (NPG - 1)) == 0) mark[p.y] = 1;
    }
    __syncthreads();
    if (fits) for (int t = tid; t < n; t += 256) col[base + t] = lout[t];
}

// seeds + marked in-neighbors -> flist
__global__ void k_compact(const int* __restrict__ mark, int* __restrict__ flist,
                          int* __restrict__ fcnt) {
    int i = blockIdx.x * 256 + threadIdx.x;
    if (((i & (NPG - 1)) == 0) || mark[i]) flist[atomicAdd(fcnt, 1)] = i;
}

// ================= GEMMs (outputs pre-scaled by dis[row], stored fp16) =================
// Tiled for DS-instruction economy: thread = 1 row x 4 cols; per k-step the wave
// issues 1 ds_read_b32 (x broadcast over 8 lanes) + 1 ds_read_b128 (W quad,
// broadcast over 8 row-groups) feeding 4 FMAs. x staged with padded stride so
// bank = (4r+k)%32 -> conflict-free.

__device__ __forceinline__ void store_h4(__half* __restrict__ h, long idx, float4 v, float d) {
    union { __half2 h2[2]; uint2 u; } pk;
    pk.h2[0] = __floats2half2_rn(v.x * d, v.y * d);
    pk.h2[1] = __floats2half2_rn(v.z * d, v.w * d);
    *reinterpret_cast<uint2*>(h + idx) = pk.u;   // idx is 4-elem aligned -> 8B aligned
}

#define XPAD0 132   // 128 + 4: bank advance 4 per row

__global__ void __launch_bounds__(256) k_gemm0(const void* __restrict__ x,
                                               const float* __restrict__ W,
                                               __half* __restrict__ h,
                                               const float* __restrict__ dis,
                                               const int* __restrict__ flag) {
    __shared__ float Wl[DD * CC];        // 16 KB, [k][c] row-major
    __shared__ float xl[32 * XPAD0];     // 16.9 KB, padded rows
    int tid = threadIdx.x;
    long rowbase = (long)blockIdx.x * 32;
    // stage W (1024 float4)
    const float4* W4 = (const float4*)W;
    float4* Wl4 = (float4*)Wl;
    for (int t = tid; t < DD * CC / 4; t += 256) Wl4[t] = W4[t];
    // stage x: 4096 elems = 1024 quads; quad t -> row r=t>>5, k0=(t&31)*4
    if (flag[0]) {
        const uint2* xv = (const uint2*)((const unsigned short*)x + rowbase * DD);
        for (int t = tid; t < 1024; t += 256) {
            uint2 u = xv[t];
            float4 v;
            v.x = __uint_as_float(u.x << 16);
            v.y = __uint_as_float(u.x & 0xffff0000u);
            v.z = __uint_as_float(u.y << 16);
            v.w = __uint_as_float(u.y & 0xffff0000u);
            *(float4*)&xl[(t >> 5) * XPAD0 + (t & 31) * 4] = v;
        }
    } else {
        const float4* xv = (const float4*)((const float*)x + rowbase * DD);
        for (int t = tid; t < 1024; t += 256)
            *(float4*)&xl[(t >> 5) * XPAD0 + (t & 31) * 4] = xv[t];
    }
    __syncthreads();
    int r = tid >> 3, c4 = tid & 7;
    float4 acc = make_float4(0.f, 0.f, 0.f, 0.f);
    const float* xr = &xl[r * XPAD0];
    #pragma unroll 8
    for (int k = 0; k < DD; k++) {
        float xv = xr[k];
        float4 wv = Wl4[k * 8 + c4];
        acc.x += xv * wv.x; acc.y += xv * wv.y;
        acc.z += xv * wv.z; acc.w += xv * wv.w;
    }
    long row = rowbase + r;
    store_h4(h, row * CC + c4 * 4, acc, dis[row]);
}

#define XPAD1 36    // 32 + 4

__global__ void __launch_bounds__(256) k_gemm32(const float* __restrict__ hin,
                                                const float* __restrict__ W,
                                                __half* __restrict__ hout,
                                                const float* __restrict__ dis) {
    __shared__ float Wl[CC * CC];        // 4 KB
    __shared__ float xl[32 * XPAD1];     // 4.6 KB
    int tid = threadIdx.x;
    long rowbase = (long)blockIdx.x * 32;
    float4* Wl4 = (float4*)Wl;
    if (tid < 256) Wl4[tid] = ((const float4*)W)[tid];
    {   // stage 32 rows x 32 cols: thread t -> row r=t>>3, quad j=t&7
        int r = tid >> 3, j = tid & 7;
        float4 v = ((const float4*)hin)[(rowbase + r) * 8 + j];
        *(float4*)&xl[r * XPAD1 + j * 4] = v;
    }
    __syncthreads();
    int r = tid >> 3, c4 = tid & 7;
    float4 acc = make_float4(0.f, 0.f, 0.f, 0.f);
    const float* xr = &xl[r * XPAD1];
    #pragma unroll
    for (int k = 0; k < CC; k++) {
        float xv = xr[k];
        float4 wv = Wl4[k * 8 + c4];
        acc.x += xv * wv.x; acc.y += xv * wv.y;
        acc.z += xv * wv.z; acc.w += xv * wv.w;
    }
    long row = rowbase + r;
    store_h4(hout, row * CC + c4 * 4, acc, dis[row]);
}

__global__ void __launch_bounds__(256) k_gemm32l(const float* __restrict__ hin,
                                                 const float* __restrict__ W,
                                                 __half* __restrict__ hout,
                                                 const float* __restrict__ dis,
                                                 const int* __restrict__ flist,
                                                 const int* __restrict__ fcnt) {
    int n = *fcnt;
    int base = blockIdx.x * 32;
    if (base >= n) return;
    __shared__ float Wl[CC * CC];
    __shared__ float xl[32 * XPAD1];
    __shared__ int rows[32];
    int tid = threadIdx.x;
    float4* Wl4 = (float4*)Wl;
    if (tid < 256) Wl4[tid] = ((const float4*)W)[tid];
    if (tid < 32) rows[tid] = (base + tid < n) ? flist[base + tid] : flist[n - 1];
    __syncthreads();
    {
        int r = tid >> 3, j = tid & 7;
        float4 v = ((const float4*)hin)[(long)rows[r] * 8 + j];
        *(float4*)&xl[r * XPAD1 + j * 4] = v;
    }
    __syncthreads();
    int r = tid >> 3, c4 = tid & 7;
    float4 acc = make_float4(0.f, 0.f, 0.f, 0.f);
    const float* xr = &xl[r * XPAD1];
    #pragma unroll
    for (int k = 0; k < CC; k++) {
        float xv = xr[k];
        float4 wv = Wl4[k * 8 + c4];
        acc.x += xv * wv.x; acc.y += xv * wv.y;
        acc.z += xv * wv.z; acc.w += xv * wv.w;
    }
    long row = rows[r];
    store_h4(hout, row * CC + c4 * 4, acc, dis[row]);
}

// ================= CSR gather-aggregate: one WAVE per dst =================
// 64 lanes = 8 edge-slots x 8 feature-quads. pbuf rows are fp16, pre-scaled by
// dis[src] -> per edge: {col load, one coalesced 64B row request}. fp32 accum.

__device__ __forceinline__ void acc_h4(float2 raw, float& ax, float& ay,
                                       float& az, float& aw) {
    __half2* h = reinterpret_cast<__half2*>(&raw);
    float2 a = __half22float2(h[0]);
    float2 b = __half22float2(h[1]);
    ax += a.x; ay += a.y; az += b.x; aw += b.y;
}

__device__ __forceinline__ float4 gat_row4(const int* __restrict__ col,
                                           const float2* __restrict__ pb,
                                           int r0, int r1, int p, int q) {
    float ax = 0.f, ay = 0.f, az = 0.f, aw = 0.f;
    int e = r0 + p;
    for (; e + 8 < r1; e += 16) {
        int s0 = col[e], s1 = col[e + 8];
        float2 v0 = pb[(long)s0 * 8 + q];
        float2 v1 = pb[(long)s1 * 8 + q];
        acc_h4(v0, ax, ay, az, aw);
        acc_h4(v1, ax, ay, az, aw);
    }
    if (e < r1) {
        float2 v = pb[(long)col[e] * 8 + q];
        acc_h4(v, ax, ay, az, aw);
    }
    #pragma unroll
    for (int m = 8; m < 64; m <<= 1) {   // combine the 8 edge-slots
        ax += __shfl_xor(ax, m);
        ay += __shfl_xor(ay, m);
        az += __shfl_xor(az, m);
        aw += __shfl_xor(aw, m);
    }
    return make_float4(ax, ay, az, aw);
}

__device__ __forceinline__ void gat_write(const float* __restrict__ dis,
                                          const float2* __restrict__ pb,
                                          const float* __restrict__ bias,
                                          float* __restrict__ hbuf,
                                          float* __restrict__ cat, int boff,
                                          int d, int q, float4 acc, bool wr_h) {
    float dd = dis[d];
    float sx = 0.f, sy = 0.f, sz = 0.f, sw = 0.f;
    acc_h4(pb[(long)d * 8 + q], sx, sy, sz, sw);   // self term, pre-scaled = dis*h
    float4 bq = ((const float4*)bias)[q];
    float4 v;
    v.x = tanhf((acc.x + sx) * dd + bq.x);
    v.y = tanhf((acc.y + sy) * dd + bq.y);
    v.z = tanhf((acc.z + sz) * dd + bq.z);
    v.w = tanhf((acc.w + sw) * dd + bq.w);
    if (wr_h) ((float4*)hbuf)[(long)d * 8 + q] = v;
    if ((d & (NPG - 1)) == 0) ((float4*)(cat + (d >> 7) * 288 + boff))[q] = v;
}

__global__ void __launch_bounds__(256) k_gat_all(const int* __restrict__ rowptr,
                                                 const int* __restrict__ col,
                                                 const float* __restrict__ dis,
                                                 const __half* __restrict__ pbuf,
                                                 const float* __restrict__ bias,
                                                 float* __restrict__ hbuf,
                                                 float* __restrict__ cat, int boff) {
    int tid = threadIdx.x;
    int d = blockIdx.x * 4 + (tid >> 6);
    int p = (tid >> 3) & 7, q = tid & 7;
    int r0 = rowptr[d], r1 = rowptr[d + 1];
    const float2* pb = (const float2*)pbuf;
    float4 acc = gat_row4(col, pb, r0, r1, p, q);
    if (p == 0) gat_write(dis, pb, bias, hbuf, cat, boff, d, q, acc, true);
}

__global__ void __launch_bounds__(256) k_gat_list(const int* __restrict__ rowptr,
                                                  const int* __restrict__ col,
                                                  const float* __restrict__ dis,
                                                  const __half* __restrict__ pbuf,
                                                  const float* __restrict__ bias,
                                                  float* __restrict__ hbuf,
                                                  float* __restrict__ cat, int boff,
                                                  const int* __restrict__ flist,
                                                  const int* __restrict__ fcnt) {
    int tid = threadIdx.x;
    int idx = blockIdx.x * 4 + (tid >> 6);
    if (idx >= *fcnt) return;
    int d = flist[idx];
    int p = (tid >> 3) & 7, q = tid & 7;
    int r0 = rowptr[d], r1 = rowptr[d + 1];
    const float2* pb = (const float2*)pbuf;
    float4 acc = gat_row4(col, pb, r0, r1, p, q);
    if (p == 0) gat_write(dis, pb, bias, hbuf, cat, boff, d, q, acc, true);
}

__global__ void __launch_bounds__(256) k_gat_seed(const int* __restrict__ rowptr,
                                                  const int* __restrict__ col,
                                                  const float* __restrict__ dis,
                                                  const __half* __restrict__ pbuf,
                                                  const float* __restrict__ bias,
                                                  float* __restrict__ cat, int boff) {
    int tid = threadIdx.x;
    int g = blockIdx.x * 4 + (tid >> 6);
    int d = g * NPG;
    int p = (tid >> 3) & 7, q = tid & 7;
    int r0 = rowptr[d], r1 = rowptr[d + 1];
    const float2* pb = (const float2*)pbuf;
    float4 acc = gat_row4(col, pb, r0, r1, p, q);
    if (p == 0) gat_write(dis, pb, bias, nullptr, cat, boff, d, q, acc, false);
}

// ================= head =================
__global__ void __launch_bounds__(128) k_head(const float* __restrict__ cat,
                                              const float* __restrict__ W1,
                                              const float* __restrict__ b1,
                                              const float* __restrict__ W2,
                                              const float* __restrict__ b2,
                                              const int* __restrict__ y,
                                              void* __restrict__ out,
                                              float* __restrict__ scal,
                                              const int* __restrict__ flag) {
    __shared__ float crow[288];
    __shared__ float red[4];
    int g = blockIdx.x, tid = threadIdx.x;
    int bfm = flag[0];
    for (int t = tid; t < 288; t += 128) crow[t] = cat[g * 288 + t];
    __syncthreads();
    float acc = 0.f;
    #pragma unroll 4
    for (int k = 0; k < 288; k++) acc += crow[k] * W1[k * 128 + tid];
    acc += b1[tid];
    if (bfm) ((bf16*)out)[2050 + g * 128 + tid] = __float2bfloat16(acc);
    else     ((float*)out)[2050 + g * 128 + tid] = acc;
    float r = fmaxf(acc, 0.f);
    float p0 = r * W2[tid * 2 + 0];
    float p1 = r * W2[tid * 2 + 1];
    for (int o = 32; o > 0; o >>= 1) {
        p0 += __shfl_down(p0, o);
        p1 += __shfl_down(p1, o);
    }
    if ((tid & 63) == 0) { red[(tid >> 6) * 2 + 0] = p0; red[(tid >> 6) * 2 + 1] = p1; }
    __syncthreads();
    if (tid == 0) {
        float l0 = red[0] + red[2] + b2[0];
        float l1 = red[1] + red[3] + b2[1];
        float m = fmaxf(l0, l1);
        float lse = m + logf(expf(l0 - m) + expf(l1 - m));
        float g0 = l0 - lse, g1 = l1 - lse;
        if (bfm) {
            ((bf16*)out)[g * 2 + 0] = __float2bfloat16(g0);
            ((bf16*)out)[g * 2 + 1] = __float2bfloat16(g1);
        } else {
            ((float*)out)[g * 2 + 0] = g0;
            ((float*)out)[g * 2 + 1] = g1;
        }
        int yy = y[g];
        atomicAdd(&scal[0], (yy == 0) ? -g0 : -g1);
        int pred = (l1 > l0) ? 1 : 0;
        if (pred == yy) atomicAdd(&scal[1], 1.0f);
    }
}

__global__ void k_fin(const float* __restrict__ scal, void* __restrict__ out,
                      const int* __restrict__ flag) {
    if (threadIdx.x == 0 && blockIdx.x == 0) {
        if (flag[0]) {
            ((bf16*)out)[2048] = __float2bfloat16(scal[0] / (float)GG);
            ((bf16*)out)[2049] = __float2bfloat16(scal[1] / (float)GG);
        } else {
            ((float*)out)[2048] = scal[0] / (float)GG;
            ((float*)out)[2049] = scal[1] / (float)GG;
        }
    }
}

extern "C" void kernel_launch(void* const* d_in, const int* in_sizes, int n_in,
                              void* d_out, int out_size, void* d_ws, size_t ws_size,
                              hipStream_t stream) {
    const void* x[3]  = {d_in[0], d_in[3], d_in[6]};
    const int*  ei[3] = {(const int*)d_in[1], (const int*)d_in[4], (const int*)d_in[7]};
    const int*  y     = (const int*)d_in[9];

    // ---- workspace carve-up ----
    int*   rowptr = (int*)d_ws;                // NN+2 (padded even)
    int*   col    = rowptr + NN + 2;           // EE
    int*   mark   = col + EE;                  // NN
    int*   flist  = mark + NN;                 // NN
    int*   fcnt   = flist + NN;                // 1
    int*   bhist  = fcnt + 1;                  // 512
    int*   bbase  = bhist + 512;               // 513
    int*   bcur   = bbase + 513;               // 512  (running total even)
    float* dis    = (float*)(bcur + 512);      // NN
    float* pbuf   = dis + NN;                  // NN*32 floats reserved; fp16 uses half } ebuf overlays
    float* hbuf   = pbuf + (size_t)NN * CC;    // NN*32 fp32                            } pbuf+hbuf
    int2*  ebuf   = (int2*)pbuf;               // EE int2 = exactly pbuf+hbuf region
    __half* pbufh = (__half*)pbuf;             // fp16 gather payload (first 8MB of pbuf region)
    float* cat    = hbuf + (size_t)NN * CC;    // GG*288 (16B-aligned)
    float* scal   = cat + (size_t)GG * 288;    // 2
    int*   flag   = (int*)(scal + 2);          // 1 (+1 pad to keep wf 16B-aligned)
    float* wf     = (float*)(flag + 2);        // 43490
    float* fWc0 = wf;
    float* fbc0 = wf + 4096;
    float* fWc1 = wf + 4128;
    float* fbc1 = wf + 5152;
    float* fWc2 = wf + 5184;
    float* fbc2 = wf + 6208;
    float* fW1  = wf + 6240;
    float* fb1  = wf + 43104;
    float* fW2  = wf + 43232;
    float* fb2  = wf + 43488;
    size_t need = (size_t)((char*)(wf + 43490) - (char*)d_ws);
    if (ws_size < need) return;   // starved: leave out zero as a diagnostic

    k_probe<<<1, 128, 0, stream>>>((const unsigned short*)x[0], flag);
    PtrPack pk;
    for (int k = 0; k < 10; k++) pk.p[k] = d_in[10 + k];
    k_cvtall<<<170, 256, 0, stream>>>(pk, wf, flag);
    hipMemsetAsync(scal, 0, 2 * sizeof(float), stream);

    const float* fW[3] = {fWc0, fWc1, fWc2};
    const float* fb[3] = {fbc0, fbc1, fbc2};

    for (int b = 0; b < 3; b++) {
        // ---- bucket-sorted CSR build ----
        hipMemsetAsync(bhist, 0, NB * sizeof(int), stream);
        hipMemsetAsync(mark, 0, NN * sizeof(int), stream);
        hipMemsetAsync(fcnt, 0, sizeof(int), stream);
        k_hist<<<512, 256, 0, stream>>>(ei[b], bhist);
        k_bscan<<<1, 512, 0, stream>>>(bhist, bbase, bcur);
        k_bin<<<EE / BTILE, 512, 0, stream>>>(ei[b], bcur, ebuf);
        k_csr<<<NB, 256, 0, stream>>>(bbase, ebuf, rowptr, col, dis, mark);
        k_compact<<<NN / 256, 256, 0, stream>>>(mark, flist, fcnt);

        // ---- layer 1: full graph ----
        k_gemm0<<<NN / 32, 256, 0, stream>>>(x[b], fW[0], pbufh, dis, flag);
        k_gat_all<<<NN / 4, 256, 0, stream>>>(rowptr, col, dis, pbufh, fb[0], hbuf, cat, b * 96);
        // ---- layer 2: frontier only ----
        k_gemm32<<<NN / 32, 256, 0, stream>>>(hbuf, fW[1], pbufh, dis);
        k_gat_list<<<NN / 4, 256, 0, stream>>>(rowptr, col, dis, pbufh, fb[1], hbuf, cat,
                                               b * 96 + 32, flist, fcnt);
        // ---- layer 3: seeds only ----
        k_gemm32l<<<NN / 32, 256, 0, stream>>>(hbuf, fW[2], pbufh, dis, flist, fcnt);
        k_gat_seed<<<GG / 4, 256, 0, stream>>>(rowptr, col, dis, pbufh, fb[2], cat, b * 96 + 64);
    }

    k_head<<<GG, 128, 0, stream>>>(cat, fW1, fb1, fW2, fb2, y, d_out, scal, flag);
    k_fin<<<1, 64, 0, stream>>>(scal, d_out, flag);
}